// Round 4
// baseline (85.576 us; speedup 1.0000x reference)
//
#include <hip/hip_runtime.h>
#include <hip/hip_bf16.h>

// MHSA window attention: B=64 windows, H=32 heads, N=256 tokens, D=16.
// One block per (b,h): 256 threads = 4 waves; wave w handles q-tiles w, w+4, w+8, w+12.
// bf16 MFMA 16x16x32, swapped QK^T (softmax rows lane-local), streamed kv-chunks.
// Q fragments loaded straight from global (no LDS); row-sum via ones-MFMA.

typedef short bf16x8 __attribute__((ext_vector_type(8)));
typedef float f32x4 __attribute__((ext_vector_type(4)));

__device__ __forceinline__ unsigned int pk2(float a, float b) {
  __hip_bfloat162 h = __float22bfloat162_rn(float2{a, b});   // v_cvt_pk_bf16_f32
  unsigned int u;
  __builtin_memcpy(&u, &h, 4);
  return u;
}

__global__ __launch_bounds__(256, 6)
void mhsa_kernel(const float* __restrict__ inp, const float* __restrict__ table,
                 float* __restrict__ out) {
  const int bh = blockIdx.x;
  const int b = bh >> 5;      // / 32 heads
  const int h = bh & 31;
  const int t = threadIdx.x;
  const int l = t & 63;       // lane
  const int w = t >> 6;       // wave
  const int g = l >> 4;       // lane group 0..3
  const int c = l & 15;       // frag col

  __shared__ short Ks[2][256][8];    // split frag-order, ds_read_b128
  __shared__ short Vt[16][264];      // V transposed [d][kv], padded rows
  __shared__ short Pf[4][2][64][8];  // per-wave P chunk in PV B-frag order (2KB/wave)
  __shared__ float tbl[128];         // bias column * log2(e)

  if (t < 127) tbl[t] = table[t * 32 + h] * 1.4426950408889634f;

  const float* gbase = inp + (size_t)b * (256 * 1536) + h * 16;

  // Q fragment loads straight from global, issued before staging so the
  // latency hides under K/V conversion. Lane (g<2, c): Q[qt*16+c][g*8..g*8+7].
  float4 qa[4] = {{0,0,0,0},{0,0,0,0},{0,0,0,0},{0,0,0,0}};
  float4 qb[4] = {{0,0,0,0},{0,0,0,0},{0,0,0,0},{0,0,0,0}};
  if (g < 2) {
    #pragma unroll
    for (int i = 0; i < 4; ++i) {
      const int qrow = (w + 4 * i) * 16 + c;
      const float* qp = gbase + (size_t)qrow * 1536 + g * 8;
      qa[i] = *(const float4*)qp;
      qb[i] = *(const float4*)(qp + 4);
    }
  }

  // K/V staging
  {
    const int row0 = t >> 2;
    const int c4 = t & 3;
    #pragma unroll
    for (int it = 0; it < 4; ++it) {
      const int row = it * 64 + row0;
      const float* p = gbase + (size_t)row * 1536 + c4 * 4;
      float4 kv = *(const float4*)(p + 512);
      float4 vv = *(const float4*)(p + 1024);
      const int dh = c4 >> 1, o4 = (c4 & 1) * 4;
      *(int2*)&Ks[dh][row][o4] = make_int2(pk2(kv.x, kv.y), pk2(kv.z, kv.w));
      unsigned int v01 = pk2(vv.x, vv.y), v23 = pk2(vv.z, vv.w);
      Vt[c4 * 4 + 0][row] = (short)(v01 & 0xffff);
      Vt[c4 * 4 + 1][row] = (short)(v01 >> 16);
      Vt[c4 * 4 + 2][row] = (short)(v23 & 0xffff);
      Vt[c4 * 4 + 3][row] = (short)(v23 >> 16);
    }
  }

  // Convert Q to bf16 B-fragments (zero for g>=2: d only 0..15)
  bf16x8 bq[4];
  #pragma unroll
  for (int i = 0; i < 4; ++i) {
    unsigned int q4[4] = { pk2(qa[i].x, qa[i].y), pk2(qa[i].z, qa[i].w),
                           pk2(qb[i].x, qb[i].y), pk2(qb[i].z, qb[i].w) };
    __builtin_memcpy(&bq[i], q4, 16);
  }

  __syncthreads();

  // V^T A-fragments: lane holds V[kv = kb*32 + g*8 + j, d = c]
  bf16x8 vf[8];
  #pragma unroll
  for (int kb = 0; kb < 8; ++kb)
    vf[kb] = *(const bf16x8*)&Vt[c][kb * 32 + g * 8];

  const float scale2 = 0.17677669529663687f * 1.4426950408889634f;  // 32^-0.5 * log2e
  const f32x4 zacc = {0.f, 0.f, 0.f, 0.f};
  const short oneb = (short)0x3F80;  // bf16 1.0
  const bf16x8 ones = {oneb, oneb, oneb, oneb, oneb, oneb, oneb, oneb};

  #pragma unroll 1
  for (int i = 0; i < 4; ++i) {
    const int qt = w + 4 * i;
    const int qbase = qt * 16;
    const bf16x8 q8 = bq[i];
    const int bidx = (qbase >> 2) + (c >> 2) + 63 - g;
    f32x4 o = zacc;
    f32x4 osum = zacc;   // ones-MFMA row sums: every reg = sum over kv for q=c
    short* pfw = &Pf[w][0][0][0];
    const short* pfr = pfw + l * 8;

    #pragma unroll
    for (int ch = 0; ch < 4; ++ch) {
      // 4 QK^T tiles -> softmax (no max-sub; values bounded) -> P chunk to LDS
      #pragma unroll
      for (int u = 0; u < 4; ++u) {
        const int tt = ch * 4 + u;
        bf16x8 ak = {0,0,0,0,0,0,0,0};
        if (g < 2) ak = *(const bf16x8*)&Ks[g][tt * 16 + c][0];
        f32x4 s4 = __builtin_amdgcn_mfma_f32_16x16x32_bf16(ak, q8, zacc, 0, 0, 0);
        const float bias = tbl[bidx - tt * 4];
        float p0 = __builtin_amdgcn_exp2f(fmaf(s4[0], scale2, bias));
        float p1 = __builtin_amdgcn_exp2f(fmaf(s4[1], scale2, bias));
        float p2 = __builtin_amdgcn_exp2f(fmaf(s4[2], scale2, bias));
        float p3 = __builtin_amdgcn_exp2f(fmaf(s4[3], scale2, bias));
        // target: Pf[u>>1][((u&1)*2+(g>>1))*16 + c][(g&1)*4 ..]
        const int off = (u >> 1) * 512 + (((u & 1) * 2 + (g >> 1)) * 16 + c) * 8 + (g & 1) * 4;
        *(int2*)(pfw + off) = make_int2(pk2(p0, p1), pk2(p2, p3));
      }
      // PV + row-sum for this chunk
      #pragma unroll
      for (int kk = 0; kk < 2; ++kk) {
        bf16x8 bp = *(const bf16x8*)(pfr + kk * 512);
        o    = __builtin_amdgcn_mfma_f32_16x16x32_bf16(vf[ch * 2 + kk], bp, o, 0, 0, 0);
        osum = __builtin_amdgcn_mfma_f32_16x16x32_bf16(ones, bp, osum, 0, 0, 0);
      }
    }

    const float inv = 1.0f / osum[0];   // per-lane: col=q on S^T, out^T and sums
    float* op = out + (size_t)(b * 256 + qbase + c) * 512 + h * 16 + g * 4;
    float4 res = { o[0] * inv, o[1] * inv, o[2] * inv, o[3] * inv };
    *(float4*)op = res;
  }
}

extern "C" void kernel_launch(void* const* d_in, const int* in_sizes, int n_in,
                              void* d_out, int out_size, void* d_ws, size_t ws_size,
                              hipStream_t stream) {
  (void)in_sizes; (void)n_in; (void)out_size; (void)d_ws; (void)ws_size;
  const float* inp = (const float*)d_in[0];
  const float* tbl = (const float*)d_in[1];
  float* out = (float*)d_out;
  hipLaunchKernelGGL(mhsa_kernel, dim3(2048), dim3(256), 0, stream, inp, tbl, out);
}

// Round 5
// 50.749 us; speedup vs baseline: 1.6863x; 1.6863x over previous
//
#include <hip/hip_runtime.h>
#include <hip/hip_bf16.h>

// MHSA window attention: B=64 windows, H=32 heads, N=256 tokens, D=16.
// One block per (b,h): 256 threads = 4 waves; wave w handles q-tiles w, w+4, w+8, w+12.
// bf16 MFMA 16x16x32, swapped QK^T (softmax rows lane-local), streamed kv-chunks.
// Q loaded from global per-tile (software pipelined); row-sum via ones-MFMA.

typedef short bf16x8 __attribute__((ext_vector_type(8)));
typedef float f32x4 __attribute__((ext_vector_type(4)));

__device__ __forceinline__ unsigned int pk2(float a, float b) {
  __hip_bfloat162 h = __float22bfloat162_rn(float2{a, b});   // v_cvt_pk_bf16_f32
  unsigned int u;
  __builtin_memcpy(&u, &h, 4);
  return u;
}

__global__ __launch_bounds__(256, 5)
void mhsa_kernel(const float* __restrict__ inp, const float* __restrict__ table,
                 float* __restrict__ out) {
  const int bh = blockIdx.x;
  const int b = bh >> 5;      // / 32 heads
  const int h = bh & 31;
  const int t = threadIdx.x;
  const int l = t & 63;       // lane
  const int w = t >> 6;       // wave
  const int g = l >> 4;       // lane group 0..3
  const int c = l & 15;       // frag col

  __shared__ short Ks[2][256][8];    // split frag-order, ds_read_b128
  __shared__ short Vt[16][264];      // V transposed [d][kv], padded rows
  __shared__ short Pf[4][2][64][8];  // per-wave P chunk in PV B-frag order (2KB/wave)
  __shared__ float tbl[128];         // bias column * log2(e)

  if (t < 127) tbl[t] = table[t * 32 + h] * 1.4426950408889634f;

  const float* gbase = inp + (size_t)b * (256 * 1536) + h * 16;

  // Q loads for tile 0, issued before staging so latency hides under K/V work.
  float4 qa = {0, 0, 0, 0}, qb = {0, 0, 0, 0};
  if (g < 2) {
    const float* qp = gbase + (size_t)(w * 16 + c) * 1536 + g * 8;
    qa = *(const float4*)qp;
    qb = *(const float4*)(qp + 4);
  }

  // K/V staging
  {
    const int row0 = t >> 2;
    const int c4 = t & 3;
    #pragma unroll
    for (int it = 0; it < 4; ++it) {
      const int row = it * 64 + row0;
      const float* p = gbase + (size_t)row * 1536 + c4 * 4;
      float4 kv = *(const float4*)(p + 512);
      float4 vv = *(const float4*)(p + 1024);
      const int dh = c4 >> 1, o4 = (c4 & 1) * 4;
      *(int2*)&Ks[dh][row][o4] = make_int2(pk2(kv.x, kv.y), pk2(kv.z, kv.w));
      unsigned int v01 = pk2(vv.x, vv.y), v23 = pk2(vv.z, vv.w);
      Vt[c4 * 4 + 0][row] = (short)(v01 & 0xffff);
      Vt[c4 * 4 + 1][row] = (short)(v01 >> 16);
      Vt[c4 * 4 + 2][row] = (short)(v23 & 0xffff);
      Vt[c4 * 4 + 3][row] = (short)(v23 >> 16);
    }
  }
  __syncthreads();

  // V^T A-fragments: lane holds V[kv = kb*32 + g*8 + j, d = c]
  bf16x8 vf[8];
  #pragma unroll
  for (int kb = 0; kb < 8; ++kb)
    vf[kb] = *(const bf16x8*)&Vt[c][kb * 32 + g * 8];

  const float scale2 = 0.17677669529663687f * 1.4426950408889634f;  // 32^-0.5 * log2e
  const f32x4 zacc = {0.f, 0.f, 0.f, 0.f};
  const short oneb = (short)0x3F80;  // bf16 1.0
  const bf16x8 ones = {oneb, oneb, oneb, oneb, oneb, oneb, oneb, oneb};

  #pragma unroll 1
  for (int i = 0; i < 4; ++i) {
    const int qt = w + 4 * i;
    const int qbase = qt * 16;

    // Convert current Q to bf16 B-frag (zero for g>=2: d only 0..15)
    bf16x8 q8 = {0, 0, 0, 0, 0, 0, 0, 0};
    if (g < 2) {
      unsigned int q4[4] = { pk2(qa.x, qa.y), pk2(qa.z, qa.w),
                             pk2(qb.x, qb.y), pk2(qb.z, qb.w) };
      __builtin_memcpy(&q8, q4, 16);
    }
    // Prefetch next tile's Q (hides under this tile's compute)
    if (i < 3 && g < 2) {
      const float* qp = gbase + (size_t)(qbase + 64 + c) * 1536 + g * 8;
      qa = *(const float4*)qp;
      qb = *(const float4*)(qp + 4);
    }

    const int bidx = (qbase >> 2) + (c >> 2) + 63 - g;
    f32x4 o = zacc;
    f32x4 osum = zacc;   // ones-MFMA row sums: every reg = sum over kv for q=c
    short* pfw = &Pf[w][0][0][0];
    const short* pfr = pfw + l * 8;

    #pragma unroll
    for (int ch = 0; ch < 4; ++ch) {
      // 4 QK^T tiles -> softmax (no max-sub; values bounded) -> P chunk to LDS
      #pragma unroll
      for (int u = 0; u < 4; ++u) {
        const int tt = ch * 4 + u;
        bf16x8 ak = {0, 0, 0, 0, 0, 0, 0, 0};
        if (g < 2) ak = *(const bf16x8*)&Ks[g][tt * 16 + c][0];
        f32x4 s4 = __builtin_amdgcn_mfma_f32_16x16x32_bf16(ak, q8, zacc, 0, 0, 0);
        const float bias = tbl[bidx - tt * 4];
        float p0 = __builtin_amdgcn_exp2f(fmaf(s4[0], scale2, bias));
        float p1 = __builtin_amdgcn_exp2f(fmaf(s4[1], scale2, bias));
        float p2 = __builtin_amdgcn_exp2f(fmaf(s4[2], scale2, bias));
        float p3 = __builtin_amdgcn_exp2f(fmaf(s4[3], scale2, bias));
        // target: Pf[u>>1][((u&1)*2+(g>>1))*16 + c][(g&1)*4 ..]
        const int off = (u >> 1) * 512 + (((u & 1) * 2 + (g >> 1)) * 16 + c) * 8 + (g & 1) * 4;
        *(int2*)(pfw + off) = make_int2(pk2(p0, p1), pk2(p2, p3));
      }
      // PV + row-sum for this chunk
      #pragma unroll
      for (int kk = 0; kk < 2; ++kk) {
        bf16x8 bp = *(const bf16x8*)(pfr + kk * 512);
        o    = __builtin_amdgcn_mfma_f32_16x16x32_bf16(vf[ch * 2 + kk], bp, o, 0, 0, 0);
        osum = __builtin_amdgcn_mfma_f32_16x16x32_bf16(ones, bp, osum, 0, 0, 0);
      }
    }

    const float inv = 1.0f / osum[0];   // per-lane: col=q on S^T, out^T and sums
    float* op = out + (size_t)(b * 256 + qbase + c) * 512 + h * 16 + g * 4;
    float4 res = { o[0] * inv, o[1] * inv, o[2] * inv, o[3] * inv };
    *(float4*)op = res;
  }
}

extern "C" void kernel_launch(void* const* d_in, const int* in_sizes, int n_in,
                              void* d_out, int out_size, void* d_ws, size_t ws_size,
                              hipStream_t stream) {
  (void)in_sizes; (void)n_in; (void)out_size; (void)d_ws; (void)ws_size;
  const float* inp = (const float*)d_in[0];
  const float* tbl = (const float*)d_in[1];
  float* out = (float*)d_out;
  hipLaunchKernelGGL(mhsa_kernel, dim3(2048), dim3(256), 0, stream, inp, tbl, out);
}

// Round 6
// 47.004 us; speedup vs baseline: 1.8206x; 1.0797x over previous
//
#include <hip/hip_runtime.h>
#include <hip/hip_bf16.h>

// MHSA window attention: B=64 windows, H=32 heads, N=256 tokens, D=16.
// One block per (b,h): 256 threads = 4 waves; wave w handles q-tiles w and w+4 (32 q each).
// mfma_f32_32x32x16_bf16: K=16 == head_dim exactly (no padding, no idle lanes).
// Swapped QK^T -> softmax lane-local; P stays in registers (permlane32_swap);
// V^T row 16 = ones -> PV accumulator reg8 IS the softmax denominator.

typedef short bf16x8 __attribute__((ext_vector_type(8)));
typedef float f32x16 __attribute__((ext_vector_type(16)));

__device__ __forceinline__ unsigned int pk2(float a, float b) {
  __hip_bfloat162 hh = __float22bfloat162_rn(float2{a, b});   // v_cvt_pk_bf16_f32
  unsigned int u; __builtin_memcpy(&u, &hh, 4); return u;
}

#if __has_builtin(__builtin_amdgcn_permlane32_swap)
typedef int i32x2_t __attribute__((ext_vector_type(2)));
__device__ __forceinline__ void swap_halves(unsigned x, unsigned y, unsigned& ox, unsigned& oy) {
  i32x2_t r = __builtin_amdgcn_permlane32_swap((int)x, (int)y, false, false);
  ox = (unsigned)r.x;   // [x.lo | y.lo]
  oy = (unsigned)r.y;   // [x.hi | y.hi]
}
#else
__device__ __forceinline__ void swap_halves(unsigned x, unsigned y, unsigned& ox, unsigned& oy) {
  const int hi = (threadIdx.x & 63) >> 5;
  unsigned tx = (unsigned)__shfl_xor((int)x, 32);
  unsigned ty = (unsigned)__shfl_xor((int)y, 32);
  ox = hi ? ty : x;
  oy = hi ? y : tx;
}
#endif

__global__ __launch_bounds__(256, 4)
void mhsa_kernel(const float* __restrict__ inp, const float* __restrict__ table,
                 float* __restrict__ out) {
  const int bh = blockIdx.x;
  const int b = bh >> 5, h = bh & 31;
  const int t = threadIdx.x;
  const int l = t & 63;
  const int w = t >> 6;
  const int q32 = l & 31;     // MFMA col (q index); also A-operand row role
  const int hi = l >> 5;      // k-group / half-wave

  __shared__ __align__(16) short KF[8][64][8];   // K fragment-order: [kv-tile32][lane][8]
  __shared__ __align__(16) short VF[16][34][8];  // V^T frag-order: [kv-chunk16][hi*17 + d][8]; d=16 row = ones
  __shared__ float tbl[128];                     // bias column * log2(e)

  if (t < 127) tbl[t] = table[t * 32 + h] * 1.4426950408889634f;
  {
    // ones rows (sum trick): VF[kb][hv*17 + 16][j] = 1.0bf16, 256 slots = 1/thread
    const int kb = t >> 4, hv = (t >> 3) & 1, j = t & 7;
    VF[kb][hv * 17 + 16][j] = (short)0x3F80;
  }

  const float* gbase = inp + (size_t)b * (256 * 1536) + h * 16;

  // Q prefetch for tile i=0: row w*32 + q32, floats hi*8 .. hi*8+7
  float4 qa, qb2;
  {
    const float* qp = gbase + (size_t)(w * 32 + q32) * 1536 + hi * 8;
    qa  = *(const float4*)qp;
    qb2 = *(const float4*)(qp + 4);
  }

  // K/V staging into fragment-order LDS
  {
    const int row0 = t >> 2, c4 = t & 3;
    #pragma unroll
    for (int it = 0; it < 4; ++it) {
      const int row = it * 64 + row0;
      const float* p = gbase + (size_t)row * 1536 + c4 * 4;
      float4 kv = *(const float4*)(p + 512);
      float4 vv = *(const float4*)(p + 1024);
      // KF[row>>5][(c4>>1)*32 + (row&31)][(c4&1)*4 ..]
      short* kdst = &KF[0][0][0] + (row >> 5) * 512 + ((c4 >> 1) * 32 + (row & 31)) * 8 + (c4 & 1) * 4;
      *(int2*)kdst = make_int2(pk2(kv.x, kv.y), pk2(kv.z, kv.w));
      // VF[row>>4][((row>>3)&1)*17 + d][row&7] for d = c4*4..c4*4+3
      unsigned int v01 = pk2(vv.x, vv.y), v23 = pk2(vv.z, vv.w);
      short* vdst = &VF[0][0][0] + (row >> 4) * 272 + (((row >> 3) & 1) * 17 + c4 * 4) * 8 + (row & 7);
      vdst[0]  = (short)(v01 & 0xffff);
      vdst[8]  = (short)(v01 >> 16);
      vdst[16] = (short)(v23 & 0xffff);
      vdst[24] = (short)(v23 >> 16);
    }
  }
  __syncthreads();

  const float scale2 = 0.17677669529663687f * 1.4426950408889634f;  // 32^-0.5 * log2e
  const f32x16 z16 = {0.f};
  const short* kfb = &KF[0][0][0] + l * 8;                       // linear: conflict-free
  const int vslot = hi * 17 + (q32 > 16 ? 16 : q32);             // d row (>=16 -> ones row)
  const short* vfb = &VF[0][0][0] + vslot * 8;

  #pragma unroll
  for (int i = 0; i < 2; ++i) {
    const int qbase = (w + 4 * i) * 32;

    // Q B-frag: col=q32, k = hi*8 + j = d
    bf16x8 q8;
    {
      unsigned int qw[4] = { pk2(qa.x, qa.y), pk2(qa.z, qa.w),
                             pk2(qb2.x, qb2.y), pk2(qb2.z, qb2.w) };
      __builtin_memcpy(&q8, qw, 16);
    }
    if (i == 0) {  // prefetch next q-tile (hides under this tile's compute)
      const float* qp = gbase + (size_t)((w + 4) * 32 + q32) * 1536 + hi * 8;
      qa  = *(const float4*)qp;
      qb2 = *(const float4*)(qp + 4);
    }

    f32x16 oacc = z16;
    const int bb = (qbase >> 2) + (q32 >> 2) + 63 - hi;

    #pragma unroll 2
    for (int kt = 0; kt < 8; ++kt) {
      // S^T tile (32kv x 32q): rows kv = kt*32 + (reg&3)+8*(reg>>2)+4*hi, col q = q32
      bf16x8 kf = *(const bf16x8*)(kfb + kt * 512);
      f32x16 s = __builtin_amdgcn_mfma_f32_32x32x16_bf16(kf, q8, z16, 0, 0, 0);

      // bias + exp2 (no max-sub: logits bounded), pack to bf16 pairs
      unsigned int wd[8];
      #pragma unroll
      for (int m = 0; m < 4; ++m) {
        const float bias = tbl[bb - kt * 8 - 2 * m];   // const over the 4 regs of quad m
        float p0 = __builtin_amdgcn_exp2f(fmaf(s[4 * m + 0], scale2, bias));
        float p1 = __builtin_amdgcn_exp2f(fmaf(s[4 * m + 1], scale2, bias));
        float p2 = __builtin_amdgcn_exp2f(fmaf(s[4 * m + 2], scale2, bias));
        float p3 = __builtin_amdgcn_exp2f(fmaf(s[4 * m + 3], scale2, bias));
        wd[2 * m]     = pk2(p0, p1);
        wd[2 * m + 1] = pk2(p2, p3);
      }

      // Assemble PV B-frags (P^T[kv16][q]) via half-wave swaps: 2 swaps per 16-kv chunk
      unsigned f0, f1, f2, f3;
      bf16x8 pf0, pf1;
      swap_halves(wd[0], wd[2], f0, f2);
      swap_halves(wd[1], wd[3], f1, f3);
      { unsigned a4[4] = { f0, f1, f2, f3 }; __builtin_memcpy(&pf0, a4, 16); }
      swap_halves(wd[4], wd[6], f0, f2);
      swap_halves(wd[5], wd[7], f1, f3);
      { unsigned a4[4] = { f0, f1, f2, f3 }; __builtin_memcpy(&pf1, a4, 16); }

      // out^T += V^T * P^T  (A row 16 = ones -> row-sum lands in reg8, hi=0)
      bf16x8 v0 = *(const bf16x8*)(vfb + (kt * 2 + 0) * 272);
      bf16x8 v1 = *(const bf16x8*)(vfb + (kt * 2 + 1) * 272);
      oacc = __builtin_amdgcn_mfma_f32_32x32x16_bf16(v0, pf0, oacc, 0, 0, 0);
      oacc = __builtin_amdgcn_mfma_f32_32x32x16_bf16(v1, pf1, oacc, 0, 0, 0);
    }

    // denominator: C row16 = reg8 of hi=0 lanes; broadcast to both halves
    const float ssum = __shfl(oacc[8], q32);
    const float inv = 1.0f / ssum;

    // C rows: regs0-3 -> d = 4*hi+ (0..3); regs4-7 -> d = 8 + 4*hi + (0..3)
    float* op = out + (size_t)(b * 256 + qbase + q32) * 512 + h * 16 + hi * 4;
    float4 r0 = { oacc[0] * inv, oacc[1] * inv, oacc[2] * inv, oacc[3] * inv };
    float4 r1 = { oacc[4] * inv, oacc[5] * inv, oacc[6] * inv, oacc[7] * inv };
    *(float4*)op = r0;
    *(float4*)(op + 8) = r1;
  }
}

extern "C" void kernel_launch(void* const* d_in, const int* in_sizes, int n_in,
                              void* d_out, int out_size, void* d_ws, size_t ws_size,
                              hipStream_t stream) {
  (void)in_sizes; (void)n_in; (void)out_size; (void)d_ws; (void)ws_size;
  const float* inp = (const float*)d_in[0];
  const float* tbl = (const float*)d_in[1];
  float* out = (float*)d_out;
  hipLaunchKernelGGL(mhsa_kernel, dim3(2048), dim3(256), 0, stream, inp, tbl, out);
}